// Round 4
// baseline (65955.939 us; speedup 1.0000x reference)
//
#include <hip/hip_runtime.h>
#include <hip/hip_cooperative_groups.h>
#include <cstddef>

namespace cg = cooperative_groups;

#define T_STEPS 16384
#define E_DIM   1024
#define H_DIM   1024
#define G4      4096

#define NRWG 128            // recurrence workgroups (blocks 0..127)
#define NGWG 128            // GEMM producer workgroups (blocks 128..255)
#define NWG_TOT (NRWG + NGWG)
#define NTH 512             // 8 waves per wg
#define EPW 8               // h elements per recurrence wg (one per wave)
#define CH  256             // timesteps per GEMM chunk
#define NCHUNK (T_STEPS / CH)
#define TKc 32
#define NSLOT 4             // h slot rotation depth (skew bound ~1; 4 safe)

#define LDA(p)    __hip_atomic_load((p), __ATOMIC_RELAXED, __HIP_MEMORY_SCOPE_AGENT)
#define STA(p, v) __hip_atomic_store((p), (v), __ATOMIC_RELAXED, __HIP_MEMORY_SCOPE_AGENT)

__device__ __forceinline__ float sigmoid_f(float x) { return 1.f / (1.f + __expf(-x)); }
__device__ __forceinline__ float tanh_f(float x) { return 1.f - 2.f / (__expf(2.f * x) + 1.f); }

// Tags: h_t lives at hslot[t%4][j] with value ((t+1)<<32)|bits (tag 0 / 0xAA.. invalid).
// xg[t][n] lives at xg2[(chunk&1)][t%CH][n] with tag chunk+1 (1..64; 0xAA.. invalid).
// All exchange via relaxed agent-scope 8B atomics: no fences, no barriers.

__global__ __launch_bounds__(NTH) void lstm_split_kernel(
    const float* __restrict__ Xs, const float* __restrict__ Wih,
    const float* __restrict__ Whh, const float* __restrict__ bih,
    const float* __restrict__ bhh, const int* __restrict__ ys,
    unsigned long long* __restrict__ xg2,    // 2 * CH * 4096 packed entries
    unsigned long long* __restrict__ hslot,  // NSLOT * 1024 packed entries
    float* __restrict__ partials,            // NRWG * T
    float* __restrict__ hy,                  // T
    float* __restrict__ wsum,                // 32
    float* __restrict__ out)                 // 1
{
    cg::grid_group grid = cg::this_grid();
    const int blk  = blockIdx.x;
    const int tid  = threadIdx.x;
    const int lane = tid & 63;

    __shared__ float hs[2][H_DIM];     // double-buffered h stage
    __shared__ float ered[2][EPW];     // per-step exp partials (parity-buffered)
    __shared__ float red[8];
    __shared__ float As[TKc][68];
    __shared__ float Bs[TKc][132];

    if (blk < NRWG) {
        // ================= recurrence path =================
        const int w  = blk;
        const int j  = tid >> 6;          // wave index == owned element offset
        const int gj = w * EPW + j;       // global h element this wave owns

        // W_hh rows for the 4 gates of element gj; k = lane + 64m
        float Wreg[4][16];
#pragma unroll
        for (int g = 0; g < 4; ++g) {
            const float* wr = Whh + (size_t)(g * H_DIM + gj) * H_DIM + lane;
#pragma unroll
            for (int m = 0; m < 16; ++m) Wreg[g][m] = wr[m << 6];
        }

        float c_state = 0.f;   // valid on lane 0 only
        if (lane == 0) STA(&hslot[gj], 1ull << 32);   // publish h_0 = 0 (tag 1)

        float xv0 = 0.f, xv1 = 0.f, xv2 = 0.f, xv3 = 0.f;
        int yt = 0;

        for (int t = 0; t < T_STEPS; ++t) {
            const int p = t & 1;
            if (lane == 0) yt = ys[t];   // issued early; used after publish

            // ---- fused poll: every thread its h pair; lane 0 also the 4 xg entries ----
            {
                const unsigned htag = (unsigned)(t + 1);
                const unsigned ctag = (unsigned)((t >> 8) + 1);
                const unsigned long long* hp =
                    hslot + ((size_t)(t & 3) << 10) + 2 * tid;
                const unsigned long long* px = xg2
                    + ((size_t)((t >> 8) & 1) * CH) * G4
                    + (size_t)(t & (CH - 1)) * G4 + gj;
                unsigned long long v0 = 0, v1 = 0;
                bool hdone = false;
                bool xdone = (lane != 0);
                for (;;) {
                    if (!hdone) {
                        v0 = LDA(hp); v1 = LDA(hp + 1);
                        hdone = ((unsigned)(v0 >> 32) == htag) &&
                                ((unsigned)(v1 >> 32) == htag);
                    }
                    if (!xdone) {
                        unsigned long long e0 = LDA(px);
                        unsigned long long e1 = LDA(px + 1024);
                        unsigned long long e2 = LDA(px + 2048);
                        unsigned long long e3 = LDA(px + 3072);
                        if (((unsigned)(e0 >> 32) == ctag) && ((unsigned)(e1 >> 32) == ctag) &&
                            ((unsigned)(e2 >> 32) == ctag) && ((unsigned)(e3 >> 32) == ctag)) {
                            xv0 = __uint_as_float((unsigned)e0);
                            xv1 = __uint_as_float((unsigned)e1);
                            xv2 = __uint_as_float((unsigned)e2);
                            xv3 = __uint_as_float((unsigned)e3);
                            xdone = true;
                        }
                    }
                    if (hdone && xdone) break;
                }
                hs[p][2 * tid]     = __uint_as_float((unsigned)v0);
                hs[p][2 * tid + 1] = __uint_as_float((unsigned)v1);
            }
            __syncthreads();   // the ONLY barrier per step

            // wave 0: flush previous step's exp-partials (off critical path-ish)
            if (j == 0 && t > 0) {
                float e = (lane < EPW) ? ered[p ^ 1][lane] : 0.f;
                e += __shfl_xor(e, 4); e += __shfl_xor(e, 2); e += __shfl_xor(e, 1);
                if (lane == 0) partials[(size_t)w * T_STEPS + (t - 1)] = e;
            }

            // ---- matvec: 4 gate rows of gj, k split 64 lanes x 16 ----
            float a0 = 0.f, a1 = 0.f, a2 = 0.f, a3 = 0.f;
#pragma unroll
            for (int m = 0; m < 16; ++m) {
                float hvv = hs[p][lane + (m << 6)];
                a0 = fmaf(Wreg[0][m], hvv, a0);
                a1 = fmaf(Wreg[1][m], hvv, a1);
                a2 = fmaf(Wreg[2][m], hvv, a2);
                a3 = fmaf(Wreg[3][m], hvv, a3);
            }
#pragma unroll
            for (int off = 32; off >= 1; off >>= 1) {
                a0 += __shfl_xor(a0, off);
                a1 += __shfl_xor(a1, off);
                a2 += __shfl_xor(a2, off);
                a3 += __shfl_xor(a3, off);
            }

            if (lane == 0) {
                float ii = sigmoid_f(a0 + xv0);
                float ff = sigmoid_f(a1 + xv1);
                float g2 = tanh_f(a2 + xv2);
                float oo = sigmoid_f(a3 + xv3);
                c_state  = fmaf(ff, c_state, ii * g2);
                float h  = oo * tanh_f(c_state);
                // publish ASAP: h_{t+1}, tag t+2, slot (t+1)%4
                STA(&hslot[((size_t)((t + 1) & 3) << 10) + gj],
                    ((unsigned long long)(unsigned)(t + 2) << 32) |
                    (unsigned long long)__float_as_uint(h));
                ered[p][j] = __expf(h);      // h in (-1,1): exp safe, no max needed
                if (gj == yt) hy[t] = h;
            }
        }

        // flush last step's partials
        __syncthreads();
        if (j == 0) {
            float e = (lane < EPW) ? ered[(T_STEPS - 1) & 1][lane] : 0.f;
            e += __shfl_xor(e, 4); e += __shfl_xor(e, 2); e += __shfl_xor(e, 1);
            if (lane == 0) partials[(size_t)w * T_STEPS + (T_STEPS - 1)] = e;
        }
        __threadfence();
        grid.sync();

        // ---- loss: wgs 0..31 cover all T ----
        if (w < 32) {
            int t = w * NTH + tid;
            float s = 0.f;
            for (int i = 0; i < NRWG; ++i) s += partials[(size_t)i * T_STEPS + t];
            float val = logf(s) - hy[t];
#pragma unroll
            for (int off = 32; off >= 1; off >>= 1) val += __shfl_xor(val, off);
            if (lane == 0) red[tid >> 6] = val;
            __syncthreads();
            if (tid == 0) {
                float s2 = 0.f;
#pragma unroll
                for (int i = 0; i < 8; ++i) s2 += red[i];
                wsum[w] = s2;
            }
        }
        __threadfence();
        grid.sync();
        if (blk == 0 && tid == 0) {
            float s = 0.f;
            for (int i = 0; i < 32; ++i) s += wsum[i];
            out[0] = s;
        }
    } else {
        // ================= GEMM producer path =================
        const int wq  = blk - NRWG;
        const int mt  = wq >> 5;            // row tile (4 x 64 rows)
        const int nt  = wq & 31;            // col tile (32 x 128 cols)
        const int n0  = nt * 128;
        const int tx4 = (tid & 31) * 4;
        const int ty4 = (tid >> 5) * 4;
        const int lrow = tid >> 3;
        const int lkg  = (tid & 7) * 4;

        float4 bias_v;
        {
            const float4 bi = *(const float4*)&bih[n0 + tx4];
            const float4 bh = *(const float4*)&bhh[n0 + tx4];
            bias_v.x = bi.x + bh.x; bias_v.y = bi.y + bh.y;
            bias_v.z = bi.z + bh.z; bias_v.w = bi.w + bh.w;
        }

        for (int c = 0; c < NCHUNK; ++c) {
            // pacing: before overwriting parity buffer (held chunk c-2), wait until
            // element 0's h tag >= (c-1)*CH+2  (=> all wgs consumed chunk c-2's xg).
            if (c >= 2) {
                if (tid == 0) {
                    const unsigned thr = (unsigned)((c - 1) * CH + 2);
                    for (;;) {
                        unsigned best = 0;
                        for (int s = 0; s < NSLOT; ++s) {
                            unsigned long long v = LDA(&hslot[(size_t)s << 10]);
                            unsigned tg = (unsigned)(v >> 32);
                            if (tg <= (unsigned)(T_STEPS + 1) && tg > best) best = tg;
                        }
                        if (best >= thr) break;
                        __builtin_amdgcn_s_sleep(8);
                    }
                }
                __syncthreads();
            }

            float acc[4][4];
#pragma unroll
            for (int i = 0; i < 4; ++i)
#pragma unroll
                for (int jj = 0; jj < 4; ++jj) acc[i][jj] = 0.f;

            const float* Arow = Xs + (size_t)(c * CH + mt * 64 + lrow) * E_DIM + lkg;

            for (int kc = 0; kc < E_DIM; kc += TKc) {
                __syncthreads();
                float4 av = *(const float4*)(Arow + kc);
                As[lkg + 0][lrow] = av.x; As[lkg + 1][lrow] = av.y;
                As[lkg + 2][lrow] = av.z; As[lkg + 3][lrow] = av.w;
#pragma unroll
                for (int rep = 0; rep < 2; ++rep) {
                    int br = rep * 64 + lrow;
                    float4 bv = *(const float4*)&Wih[(size_t)(n0 + br) * E_DIM + kc + lkg];
                    Bs[lkg + 0][br] = bv.x; Bs[lkg + 1][br] = bv.y;
                    Bs[lkg + 2][br] = bv.z; Bs[lkg + 3][br] = bv.w;
                }
                __syncthreads();
#pragma unroll
                for (int kk = 0; kk < TKc; ++kk) {
                    float4 a = *(const float4*)&As[kk][ty4];
                    float4 b = *(const float4*)&Bs[kk][tx4];
                    acc[0][0] = fmaf(a.x, b.x, acc[0][0]); acc[0][1] = fmaf(a.x, b.y, acc[0][1]);
                    acc[0][2] = fmaf(a.x, b.z, acc[0][2]); acc[0][3] = fmaf(a.x, b.w, acc[0][3]);
                    acc[1][0] = fmaf(a.y, b.x, acc[1][0]); acc[1][1] = fmaf(a.y, b.y, acc[1][1]);
                    acc[1][2] = fmaf(a.y, b.z, acc[1][2]); acc[1][3] = fmaf(a.y, b.w, acc[1][3]);
                    acc[2][0] = fmaf(a.z, b.x, acc[2][0]); acc[2][1] = fmaf(a.z, b.y, acc[2][1]);
                    acc[2][2] = fmaf(a.z, b.z, acc[2][2]); acc[2][3] = fmaf(a.z, b.w, acc[2][3]);
                    acc[3][0] = fmaf(a.w, b.x, acc[3][0]); acc[3][1] = fmaf(a.w, b.y, acc[3][1]);
                    acc[3][2] = fmaf(a.w, b.z, acc[3][2]); acc[3][3] = fmaf(a.w, b.w, acc[3][3]);
                }
            }

            unsigned long long* xb = xg2 + ((size_t)(c & 1) * CH) * G4;
            const unsigned long long tg = (unsigned long long)(unsigned)(c + 1) << 32;
#pragma unroll
            for (int i = 0; i < 4; ++i) {
                int lr = mt * 64 + ty4 + i;
                size_t base = (size_t)lr * G4 + n0 + tx4;
                float o0 = acc[i][0] + bias_v.x;
                float o1 = acc[i][1] + bias_v.y;
                float o2 = acc[i][2] + bias_v.z;
                float o3 = acc[i][3] + bias_v.w;
                STA(&xb[base + 0], tg | (unsigned long long)__float_as_uint(o0));
                STA(&xb[base + 1], tg | (unsigned long long)__float_as_uint(o1));
                STA(&xb[base + 2], tg | (unsigned long long)__float_as_uint(o2));
                STA(&xb[base + 3], tg | (unsigned long long)__float_as_uint(o3));
            }
        }
        grid.sync();   // match recurrence epilogue sync #1
        grid.sync();   // match recurrence epilogue sync #2
    }
}

// ---------------- launch ----------------
extern "C" void kernel_launch(void* const* d_in, const int* in_sizes, int n_in,
                              void* d_out, int out_size, void* d_ws, size_t ws_size,
                              hipStream_t stream)
{
    const float* Xs  = (const float*)d_in[0];
    const float* Wih = (const float*)d_in[1];
    const float* Whh = (const float*)d_in[2];
    const float* bih = (const float*)d_in[3];
    const float* bhh = (const float*)d_in[4];
    const int*   ys  = (const int*)d_in[5];

    // workspace: 16MB xg2 + 32KB hslot + 8MB partials + 64KB hy + 128B wsum ~= 24.6 MiB
    unsigned long long* xg2   = (unsigned long long*)d_ws;
    unsigned long long* hslot = xg2 + (size_t)2 * CH * G4;
    float* partials           = (float*)(hslot + (size_t)NSLOT * H_DIM);
    float* hy                 = partials + (size_t)NRWG * T_STEPS;
    float* wsum               = hy + T_STEPS;
    float* out                = (float*)d_out;

    void* args[] = {(void*)&Xs, (void*)&Wih, (void*)&Whh, (void*)&bih, (void*)&bhh,
                    (void*)&ys, (void*)&xg2, (void*)&hslot, (void*)&partials,
                    (void*)&hy, (void*)&wsum, (void*)&out};
    hipLaunchCooperativeKernel((void*)lstm_split_kernel,
                               dim3(NWG_TOT), dim3(NTH), args, 0, stream);
}

// Round 5
// 36103.183 us; speedup vs baseline: 1.8269x; 1.8269x over previous
//
#include <hip/hip_runtime.h>
#include <hip/hip_cooperative_groups.h>
#include <cstddef>

namespace cg = cooperative_groups;

#define T_STEPS 16384
#define E_DIM   1024
#define H_DIM   1024
#define G4      4096

#define NWG 128             // cooperative workgroups (all do GEMM + recurrence)
#define NTH 512             // 8 waves per wg
#define EPW 8               // h elements per wg (one per wave)
#define CH  512             // timesteps per GEMM chunk (xgc = CH*4096 fp32 = 8 MiB)
#define NCHUNK (T_STEPS / CH)
#define TKc 32

#define LDA(p)    __hip_atomic_load((p), __ATOMIC_RELAXED, __HIP_MEMORY_SCOPE_AGENT)
#define STA(p, v) __hip_atomic_store((p), (v), __ATOMIC_RELAXED, __HIP_MEMORY_SCOPE_AGENT)

// h exchange: h_t at hslot[(t&3)<<10 | j], value ((t+1)<<32)|bits.
// Tags 1..16385; 0xAAAAAAAA poison never matches. Relaxed agent atomics, no fences.

__global__ __launch_bounds__(NTH) void lstm_fused_kernel(
    const float* __restrict__ Xs, const float* __restrict__ Wih,
    const float* __restrict__ Whh, const float* __restrict__ bih,
    const float* __restrict__ bhh, const int* __restrict__ ys,
    float* __restrict__ xgc,                 // CH*4096 floats (per-chunk buffer)
    unsigned long long* __restrict__ hslot,  // 4*1024 packed entries
    float* __restrict__ partials,            // NWG*T
    float* __restrict__ hy,                  // T
    float* __restrict__ wsum,                // 32
    float* __restrict__ out)                 // 1
{
    cg::grid_group grid = cg::this_grid();
    const int w    = blockIdx.x;
    const int tid  = threadIdx.x;
    const int lane = tid & 63;
    const int j    = tid >> 6;        // wave index == owned element offset
    const int gj   = w * EPW + j;     // global h element this wave owns

    __shared__ float hs[2][H_DIM];    // double-buffered h stage
    __shared__ float ered[16][EPW];   // exp partials ring (16 steps deep)
    __shared__ float red[8];
    __shared__ float As[TKc][68];
    __shared__ float Bs[TKc][132];

    // ---- W_hh rows for the 4 gates of element gj; k = lane + 64m ----
    float Wreg[4][16];
#pragma unroll
    for (int g = 0; g < 4; ++g) {
        const float* wr = Whh + (size_t)(g * H_DIM + gj) * H_DIM + lane;
#pragma unroll
        for (int m = 0; m < 16; ++m) Wreg[g][m] = wr[m << 6];
    }

    float c_state = 0.f;                              // meaningful on lane 0
    if (lane == 0) STA(&hslot[gj], 1ull << 32);       // publish h_0 = 0 (tag 1)

    // ---- GEMM tile mapping: wg -> two 64x128 tiles of a 512x4096 chunk ----
    const int nt   = w & 31;            // col tile
    const int n0   = nt * 128;
    const int tx4  = (tid & 31) * 4;
    const int ty4  = (tid >> 5) * 4;
    const int lrow = tid >> 3;
    const int lkg  = (tid & 7) * 4;

    float4 bias_v;
    {
        const float4 bi = *(const float4*)&bih[n0 + tx4];
        const float4 bh = *(const float4*)&bhh[n0 + tx4];
        bias_v.x = bi.x + bh.x; bias_v.y = bi.y + bh.y;
        bias_v.z = bi.z + bh.z; bias_v.w = bi.w + bh.w;
    }

    const float gate_scale = (lane == 2) ? 2.f : 1.f;   // tanh via sigma(2x)
    const float gate_mul   = (lane == 2) ? 2.f : 1.f;
    const float gate_add   = (lane == 2) ? -1.f : 0.f;

    float xv = 0.f;   // xg for current step (lanes 0..3: gate = lane)
    int   yt = 0;

    for (int c = 0; c < NCHUNK; ++c) {
        const int t0 = c * CH;

        // ================= GEMM phase: xgc = Xs[t0:t0+CH] @ Wih^T + bias =================
#pragma unroll
        for (int rep = 0; rep < 2; ++rep) {
            const int mt = (w >> 5) + rep * 4;   // row tile 0..7
            float acc[4][4];
#pragma unroll
            for (int i = 0; i < 4; ++i)
#pragma unroll
                for (int jj = 0; jj < 4; ++jj) acc[i][jj] = 0.f;

            const float* Arow = Xs + (size_t)(t0 + mt * 64 + lrow) * E_DIM + lkg;

            for (int kc = 0; kc < E_DIM; kc += TKc) {
                __syncthreads();
                float4 av = *(const float4*)(Arow + kc);
                As[lkg + 0][lrow] = av.x; As[lkg + 1][lrow] = av.y;
                As[lkg + 2][lrow] = av.z; As[lkg + 3][lrow] = av.w;
#pragma unroll
                for (int r2 = 0; r2 < 2; ++r2) {
                    int br = r2 * 64 + lrow;
                    float4 bv = *(const float4*)&Wih[(size_t)(n0 + br) * E_DIM + kc + lkg];
                    Bs[lkg + 0][br] = bv.x; Bs[lkg + 1][br] = bv.y;
                    Bs[lkg + 2][br] = bv.z; Bs[lkg + 3][br] = bv.w;
                }
                __syncthreads();
#pragma unroll
                for (int kk = 0; kk < TKc; ++kk) {
                    float4 a = *(const float4*)&As[kk][ty4];
                    float4 b = *(const float4*)&Bs[kk][tx4];
                    acc[0][0] = fmaf(a.x, b.x, acc[0][0]); acc[0][1] = fmaf(a.x, b.y, acc[0][1]);
                    acc[0][2] = fmaf(a.x, b.z, acc[0][2]); acc[0][3] = fmaf(a.x, b.w, acc[0][3]);
                    acc[1][0] = fmaf(a.y, b.x, acc[1][0]); acc[1][1] = fmaf(a.y, b.y, acc[1][1]);
                    acc[1][2] = fmaf(a.y, b.z, acc[1][2]); acc[1][3] = fmaf(a.y, b.w, acc[1][3]);
                    acc[2][0] = fmaf(a.z, b.x, acc[2][0]); acc[2][1] = fmaf(a.z, b.y, acc[2][1]);
                    acc[2][2] = fmaf(a.z, b.z, acc[2][2]); acc[2][3] = fmaf(a.z, b.w, acc[2][3]);
                    acc[3][0] = fmaf(a.w, b.x, acc[3][0]); acc[3][1] = fmaf(a.w, b.y, acc[3][1]);
                    acc[3][2] = fmaf(a.w, b.z, acc[3][2]); acc[3][3] = fmaf(a.w, b.w, acc[3][3]);
                }
            }
#pragma unroll
            for (int i = 0; i < 4; ++i) {
                int lr = mt * 64 + ty4 + i;   // chunk-local row
                float4 ov;
                ov.x = acc[i][0] + bias_v.x; ov.y = acc[i][1] + bias_v.y;
                ov.z = acc[i][2] + bias_v.z; ov.w = acc[i][3] + bias_v.w;
                *(float4*)&xgc[(size_t)lr * G4 + n0 + tx4] = ov;
            }
        }
        __threadfence();
        grid.sync();   // xgc visible to all wgs (once per 512 steps)

        // xg for first step of chunk (lanes 0..3: one gate each)
        if (lane < 4) xv = xgc[lane * H_DIM + gj];

        // ================= recurrence: CH steps, one __syncthreads each =================
        for (int lt = 0; lt < CH; ++lt) {
            const int t = t0 + lt;
            const int p = t & 1;

            if (lane == 0) yt = ys[t];   // off-path; consumed post-publish

            // ---- poll own h pair until tags match ----
            {
                const unsigned htag = (unsigned)(t + 1);
                const unsigned long long* hp =
                    hslot + ((size_t)(t & 3) << 10) + 2 * tid;
                unsigned long long v0, v1;
                do {
                    v0 = LDA(hp);
                    v1 = LDA(hp + 1);
                } while ((unsigned)(v0 >> 32) != htag || (unsigned)(v1 >> 32) != htag);
                hs[p][2 * tid]     = __uint_as_float((unsigned)v0);
                hs[p][2 * tid + 1] = __uint_as_float((unsigned)v1);
            }
            __syncthreads();   // the only barrier per step

            // ---- batched exp-partial flush: every 8 steps, rotating wave ----
            if ((t & 7) == 0 && t >= 8 && j == ((t >> 3) & 7)) {
                const int b = t - 8;
                float e = ered[(b & 15) + (lane >> 3)][lane & 7];
                e += __shfl_xor(e, 1);
                e += __shfl_xor(e, 2);
                e += __shfl_xor(e, 4);
                if ((lane & 7) == 0)
                    partials[(size_t)w * T_STEPS + b + (lane >> 3)] = e;
            }

            // ---- prefetch next step's xg into regs (off critical path) ----
            float xn = 0.f;
            if (lane < 4 && lt + 1 < CH)
                xn = xgc[(size_t)(lt + 1) * G4 + lane * H_DIM + gj];

            // ---- matvec: 4 gate rows of gj ----
            float a0 = 0.f, a1 = 0.f, a2 = 0.f, a3 = 0.f;
#pragma unroll
            for (int m = 0; m < 16; ++m) {
                float hvv = hs[p][lane + (m << 6)];
                a0 = fmaf(Wreg[0][m], hvv, a0);
                a1 = fmaf(Wreg[1][m], hvv, a1);
                a2 = fmaf(Wreg[2][m], hvv, a2);
                a3 = fmaf(Wreg[3][m], hvv, a3);
            }
#pragma unroll
            for (int off = 32; off >= 1; off >>= 1) {
                a0 += __shfl_xor(a0, off);
                a1 += __shfl_xor(a1, off);
                a2 += __shfl_xor(a2, off);
                a3 += __shfl_xor(a3, off);
            }

            // ---- parallel activations: lane g computes gate g ----
            float sel = (lane == 1) ? a1 : (lane == 2) ? a2 : (lane == 3) ? a3 : a0;
            float x   = sel + xv;
            float sg  = 1.f / (1.f + __expf(-gate_scale * x));
            float act = fmaf(sg, gate_mul, gate_add);   // sigma or tanh

            float ii = act;                // lane 0's own (gate i)
            float ff = __shfl(act, 1);
            float gg = __shfl(act, 2);
            float oo = __shfl(act, 3);
            c_state  = fmaf(ff, c_state, ii * gg);
            float tc = 2.f / (1.f + __expf(-2.f * c_state)) - 1.f;
            float h  = oo * tc;

            if (lane == 0) {
                // publish ASAP: h_{t+1} tag t+2, slot (t+1)&3
                STA(&hslot[((size_t)((t + 1) & 3) << 10) + gj],
                    ((unsigned long long)(unsigned)(t + 2) << 32) |
                    (unsigned long long)__float_as_uint(h));
                ered[t & 15][j] = __expf(h);   // h in (-1,1): exp safe
                if (gj == yt) hy[t] = h;
            }
            xv = xn;
        }
    }

    // final exp-partial flush (steps T-8 .. T-1)
    __syncthreads();
    if (j == 0) {
        const int b = T_STEPS - 8;
        float e = ered[(b & 15) + (lane >> 3)][lane & 7];
        e += __shfl_xor(e, 1);
        e += __shfl_xor(e, 2);
        e += __shfl_xor(e, 4);
        if ((lane & 7) == 0)
            partials[(size_t)w * T_STEPS + b + (lane >> 3)] = e;
    }
    __threadfence();
    grid.sync();

    // ================= loss: wgs 0..31 cover all T =================
    if (w < 32) {
        int t = w * NTH + tid;
        float s = 0.f;
        for (int i = 0; i < NWG; ++i) s += partials[(size_t)i * T_STEPS + t];
        float val = logf(s) - hy[t];
#pragma unroll
        for (int off = 32; off >= 1; off >>= 1) val += __shfl_xor(val, off);
        if (lane == 0) red[tid >> 6] = val;
        __syncthreads();
        if (tid == 0) {
            float s2 = 0.f;
#pragma unroll
            for (int i = 0; i < 8; ++i) s2 += red[i];
            wsum[w] = s2;
        }
    }
    __threadfence();
    grid.sync();
    if (w == 0 && tid == 0) {
        float s = 0.f;
        for (int i = 0; i < 32; ++i) s += wsum[i];
        out[0] = s;
    }
}

// ---------------- launch ----------------
extern "C" void kernel_launch(void* const* d_in, const int* in_sizes, int n_in,
                              void* d_out, int out_size, void* d_ws, size_t ws_size,
                              hipStream_t stream)
{
    const float* Xs  = (const float*)d_in[0];
    const float* Wih = (const float*)d_in[1];
    const float* Whh = (const float*)d_in[2];
    const float* bih = (const float*)d_in[3];
    const float* bhh = (const float*)d_in[4];
    const int*   ys  = (const int*)d_in[5];

    // workspace: 8MB xgc + 32KB hslot + 8MB partials + 64KB hy + 128B ~= 16.1 MiB
    float* xgc                = (float*)d_ws;
    unsigned long long* hslot = (unsigned long long*)(xgc + (size_t)CH * G4);
    float* partials           = (float*)(hslot + 4 * H_DIM);
    float* hy                 = partials + (size_t)NWG * T_STEPS;
    float* wsum               = hy + T_STEPS;
    float* out                = (float*)d_out;

    void* args[] = {(void*)&Xs, (void*)&Wih, (void*)&Whh, (void*)&bih, (void*)&bhh,
                    (void*)&ys, (void*)&xgc, (void*)&hslot, (void*)&partials,
                    (void*)&hy, (void*)&wsum, (void*)&out};
    hipLaunchCooperativeKernel((void*)lstm_fused_kernel,
                               dim3(NWG), dim3(NTH), args, 0, stream);
}